// Round 2
// baseline (359.092 us; speedup 1.0000x reference)
//
#include <hip/hip_runtime.h>
#include <hip/hip_bf16.h>

#define BB 32
#define CC 256
#define CQK 32
#define LL 1024
#define OTOT 320

// ---------------- workspace layout ----------------
// float region:
#define WCAT_OFF 0
#define BCAT_OFF (OTOT * CC)                 // 81920
#define QK_OFF   (BCAT_OFF + OTOT)           // 82240
#define QK_SIZE  (BB * 64 * LL)              // 2097152
#define US_BASE  (QK_OFF + QK_SIZE)          // 2179392 floats (byte 8717568, 16B aligned)
// ushort region (offsets in ushorts from US_BASE):
#define VBF_OFF   ((size_t)0)
#define WVBF_OFF  (VBF_OFF + (size_t)BB * CC * LL)        // 8388608
#define XT_OFF    (WVBF_OFF + (size_t)CC * CC)
#define KTH_OFF   (XT_OFF + (size_t)BB * LL * CC)
#define KTL_OFF   (KTH_OFF + (size_t)BB * LL * 32)

typedef __bf16 bf16x8 __attribute__((ext_vector_type(8)));
typedef float f32x4 __attribute__((ext_vector_type(4)));

__device__ inline void async_ld16(const void* g, void* l) {
  __builtin_amdgcn_global_load_lds(
      (const __attribute__((address_space(1))) void*)g,
      (__attribute__((address_space(3))) void*)l, 16, 0, 0);
}

__device__ inline ushort f2bu(float f) {
  union { __hip_bfloat16 h; ushort u; } c;
  c.h = __float2bfloat16(f);
  return c.u;
}
__device__ inline float bu2f(ushort u) {
  union { __hip_bfloat16 h; ushort u; } c;
  c.u = u;
  return __bfloat162float(c.h);
}

// ---------------------------------------------------------------- pack W+b
__global__ __launch_bounds__(256) void pack_w_kernel(
    const float* __restrict__ Wq, const float* __restrict__ bq,
    const float* __restrict__ Wk, const float* __restrict__ bk,
    const float* __restrict__ Wv, const float* __restrict__ bv,
    float* __restrict__ Wcat, float* __restrict__ bcat,
    ushort* __restrict__ Wvbf) {
  int o = blockIdx.x;
  int c = threadIdx.x;
  float w = (o < CQK) ? Wq[o * CC + c]
          : (o < 2 * CQK) ? Wk[(o - CQK) * CC + c]
          : Wv[(o - 2 * CQK) * CC + c];
  Wcat[o * CC + c] = w;
  if (o >= 64) Wvbf[(o - 64) * CC + c] = f2bu(w);
  if (c == 0) {
    bcat[o] = (o < CQK) ? bq[o] : (o < 2 * CQK) ? bk[o - CQK] : bv[o - 2 * CQK];
  }
}

// -------------------------------------------- x transpose: [b][c][l] -> bf16 [b][l][c]
__global__ __launch_bounds__(256) void xT_kernel(
    const float* __restrict__ x, ushort* __restrict__ xT) {
  __shared__ float t[64][65];
  int b = blockIdx.z, c0 = blockIdx.y * 64, l0 = blockIdx.x * 64;
  int tid = threadIdx.x;
  int r = tid >> 4, c4 = (tid & 15) * 4;
  const float* xb = x + ((size_t)b * CC + c0) * LL + l0;
#pragma unroll
  for (int i = 0; i < 4; ++i) {
    float4 v = *(const float4*)&xb[(size_t)(r + i * 16) * LL + c4];
    t[r + i * 16][c4 + 0] = v.x;
    t[r + i * 16][c4 + 1] = v.y;
    t[r + i * 16][c4 + 2] = v.z;
    t[r + i * 16][c4 + 3] = v.w;
  }
  __syncthreads();
  ushort* xo = xT + ((size_t)b * LL + l0) * CC + c0;
#pragma unroll
  for (int i = 0; i < 4; ++i) {
    int l = r + i * 16;
    ushort4 u;
    u.x = f2bu(t[c4 + 0][l]);
    u.y = f2bu(t[c4 + 1][l]);
    u.z = f2bu(t[c4 + 2][l]);
    u.w = f2bu(t[c4 + 3][l]);
    *(ushort4*)&xo[(size_t)l * CC + c4] = u;
  }
}

// ------------------------------------------------- q/k projection (fp32 VALU)
#define PPITCH 68
__global__ __launch_bounds__(256) void proj_qk_kernel(
    const float* __restrict__ x, const float* __restrict__ Wcat,
    const float* __restrict__ bcat, float* __restrict__ qk) {
  __shared__ float ws[32][PPITCH];
  __shared__ float xs[32][PPITCH];
  int b = blockIdx.z;
  int l0 = blockIdx.x * 64;
  int tid = threadIdx.x;
  int tx = tid & 15, ty = tid >> 4;
  const float* xb = x + (size_t)b * CC * LL;
  float acc[4][4] = {};

  for (int c0 = 0; c0 < CC; c0 += 32) {
    __syncthreads();
    {
      int o = tid >> 5;
      int kk = tid & 31;
#pragma unroll
      for (int r = 0; r < 8; ++r)
        ws[kk][o + 8 * r] = Wcat[(o + 8 * r) * CC + c0 + kk];
      int l = tid & 63;
      int k4 = tid >> 6;
#pragma unroll
      for (int r = 0; r < 8; ++r)
        xs[k4 + 4 * r][l] = xb[(size_t)(c0 + k4 + 4 * r) * LL + l0 + l];
    }
    __syncthreads();
#pragma unroll 8
    for (int kk = 0; kk < 32; ++kk) {
      float a[4], bvv[4];
      *(float4*)a = *(const float4*)&ws[kk][ty * 4];
      *(float4*)bvv = *(const float4*)&xs[kk][tx * 4];
#pragma unroll
      for (int i = 0; i < 4; ++i)
#pragma unroll
        for (int j = 0; j < 4; ++j)
          acc[i][j] = fmaf(a[i], bvv[j], acc[i][j]);
    }
  }
#pragma unroll
  for (int i = 0; i < 4; ++i) {
    int o = ty * 4 + i;
    float bias = bcat[o];
    float4 r;
    r.x = acc[i][0] + bias;
    r.y = acc[i][1] + bias;
    r.z = acc[i][2] + bias;
    r.w = acc[i][3] + bias;
    *(float4*)&qk[((size_t)b * 64 + o) * LL + l0 + tx * 4] = r;
  }
}

// ---------------- pack k rows into B-fragment order, hi/lo bf16
// kTp[b][jt][(q*16+ln)*8+jj] = k[b][k=q*8+jj][j=jt*16+ln]
__global__ __launch_bounds__(256) void kT_pack_kernel(
    const float* __restrict__ qk, ushort* __restrict__ kth,
    ushort* __restrict__ ktl) {
  __shared__ float ks[32][257];
  int b = blockIdx.y, jg = blockIdx.x;  // col group of 256
  int tid = threadIdx.x;
  const float* kb = qk + ((size_t)b * 64 + CQK) * LL + jg * 256;
#pragma unroll
  for (int i = 0; i < 8; ++i) {
    int row = i * 4 + (tid >> 6);
    int col4 = (tid & 63) * 4;
    float4 v = *(const float4*)&kb[(size_t)row * LL + col4];
    ks[row][col4 + 0] = v.x;
    ks[row][col4 + 1] = v.y;
    ks[row][col4 + 2] = v.z;
    ks[row][col4 + 3] = v.w;
  }
  __syncthreads();
#pragma unroll
  for (int rep = 0; rep < 4; ++rep) {
    int idx = rep * 256 + tid;            // 0..1023
    int jt_l = idx >> 6;                  // 0..15
    int q = (idx >> 4) & 3;
    int l16 = idx & 15;
    ushort h[8], lo[8];
#pragma unroll
    for (int jj = 0; jj < 8; ++jj) {
      float v = ks[q * 8 + jj][jt_l * 16 + l16];
      ushort hh = f2bu(v);
      h[jj] = hh;
      lo[jj] = f2bu(v - bu2f(hh));
    }
    size_t off = (((size_t)b * 64 + jg * 16 + jt_l) * 64 + (idx & 63)) * 8;
    *(ushort4*)&kth[off] = *(ushort4*)&h[0];
    *(ushort4*)&kth[off + 4] = *(ushort4*)&h[4];
    *(ushort4*)&ktl[off] = *(ushort4*)&lo[0];
    *(ushort4*)&ktl[off + 4] = *(ushort4*)&lo[4];
  }
}

// ---------------- v projection: vbf[b][c][l] = bf16( Wv·x + bv ), MFMA
// (round-0 verified single-buffer structure)
__global__ __launch_bounds__(256) void v_mfma_kernel(
    const ushort* __restrict__ Wvbf, const ushort* __restrict__ xT,
    const float* __restrict__ bv, ushort* __restrict__ vbf) {
  __shared__ ushort As[128 * 32];
  __shared__ ushort Bs[128 * 32];
  int b = blockIdx.z;
  int c0 = blockIdx.y * 128;
  int l0 = blockIdx.x * 128;
  int tid = threadIdx.x;
  int wave = tid >> 6, lane = tid & 63;
  int quad = lane >> 4, ln = lane & 15;
  int wr = (wave >> 1) * 64;
  int wc = (wave & 1) * 64;
  const ushort* xb = xT + (size_t)b * LL * CC;
  int r0 = tid >> 2, r1 = r0 + 64;
  int cq = (tid & 3) * 8;
  ushort* lA0 = As + (size_t)(wave * 64) * 8;
  ushort* lA1 = As + (size_t)(256 + wave * 64) * 8;
  ushort* lB0 = Bs + (size_t)(wave * 64) * 8;
  ushort* lB1 = Bs + (size_t)(256 + wave * 64) * 8;

  f32x4 acc[4][4];
#pragma unroll
  for (int i = 0; i < 4; ++i)
#pragma unroll
    for (int j = 0; j < 4; ++j) acc[i][j] = {0.f, 0.f, 0.f, 0.f};

  for (int kt = 0; kt < CC; kt += 32) {
    __syncthreads();
    async_ld16(Wvbf + (size_t)(c0 + r0) * CC + kt + cq, lA0);
    async_ld16(Wvbf + (size_t)(c0 + r1) * CC + kt + cq, lA1);
    async_ld16(xb + (size_t)(l0 + r0) * CC + kt + cq, lB0);
    async_ld16(xb + (size_t)(l0 + r1) * CC + kt + cq, lB1);
    __syncthreads();
    bf16x8 af[4], bfr[4];
#pragma unroll
    for (int i = 0; i < 4; ++i)
      af[i] = *(const bf16x8*)&As[(size_t)(wr + i * 16 + ln) * 32 + quad * 8];
#pragma unroll
    for (int j = 0; j < 4; ++j)
      bfr[j] = *(const bf16x8*)&Bs[(size_t)(wc + j * 16 + ln) * 32 + quad * 8];
#pragma unroll
    for (int i = 0; i < 4; ++i)
#pragma unroll
      for (int j = 0; j < 4; ++j)
        acc[i][j] = __builtin_amdgcn_mfma_f32_16x16x32_bf16(af[i], bfr[j], acc[i][j], 0, 0, 0);
  }

  ushort* vb = vbf + (size_t)b * CC * LL;
#pragma unroll
  for (int i = 0; i < 4; ++i) {
#pragma unroll
    for (int r = 0; r < 4; ++r) {
      int c = c0 + wr + i * 16 + quad * 4 + r;
      float bias = bv[c];
#pragma unroll
      for (int j = 0; j < 4; ++j) {
        int l = l0 + wc + j * 16 + ln;
        vb[(size_t)c * LL + l] = f2bu(acc[i][j][r] + bias);
      }
    }
  }
}

// ---------------- fused scores + softmax + PV + residual
// block: 16 att rows (m-tile) x 1024 cols; wave w owns cols [w*256, w*256+256)
// for the S phase, then owns c-range [w*64, w*64+64) for the PV phase.
// P (bf16 softmax rows) is transposed through a 32KB LDS buffer that
// time-shares with the S-phase K staging buffer (union).  attbf / out_mfma
// are eliminated: -67MB HBM write, -~70-130MB HBM read vs round-0.
__global__ __launch_bounds__(256) void attn_fused_kernel(
    const float* __restrict__ qk, const ushort* __restrict__ kth,
    const ushort* __restrict__ ktl, const ushort* __restrict__ vbf,
    const float* __restrict__ x, const float* __restrict__ gamma,
    float* __restrict__ att, float* __restrict__ out) {
  __shared__ float qs[32][17];
  __shared__ float red[4][16];
  // union: S phase = kbuf[4 waves][hi/lo][2048]; PV phase = P_lds[16][1024] (swizzled)
  __shared__ ushort shm[16 * 1024];
  int b = blockIdx.y;
  int i0 = blockIdx.x * 16;
  int tid = threadIdx.x;
  int wave = tid >> 6, lane = tid & 63;
  int quad = lane >> 4, ln = lane & 15;

  // stage q tile [32 d][16 rows]
  const float* qb = qk + (size_t)b * 64 * LL;
  {
    int e0 = tid, e1 = tid + 256;
    qs[e0 >> 4][e0 & 15] = qb[(size_t)(e0 >> 4) * LL + i0 + (e0 & 15)];
    qs[e1 >> 4][e1 & 15] = qb[(size_t)(e1 >> 4) * LL + i0 + (e1 & 15)];
  }
  __syncthreads();

  // A fragments hi/lo: A[m=ln][k=quad*8+jj]
  bf16x8 ahi, alo;
  {
    union { bf16x8 v; ushort u[8]; } H, L;
#pragma unroll
    for (int jj = 0; jj < 8; ++jj) {
      float v = qs[quad * 8 + jj][ln];
      ushort hh = f2bu(v);
      H.u[jj] = hh;
      L.u[jj] = f2bu(v - bu2f(hh));
    }
    ahi = H.v;
    alo = L.v;
  }

  const ushort* khB = kth + (size_t)b * LL * 32;
  const ushort* klB = ktl + (size_t)b * LL * 32;
  ushort* lh = shm + wave * 4096;
  ushort* llo = lh + 2048;

  f32x4 acc[16];
#pragma unroll
  for (int f = 0; f < 16; ++f) acc[f] = {0.f, 0.f, 0.f, 0.f};

  for (int ct = 0; ct < 4; ++ct) {
    int jt0 = wave * 16 + ct * 4;
    const ushort* gh = khB + (size_t)jt0 * 512;
    const ushort* gl = klB + (size_t)jt0 * 512;
#pragma unroll
    for (int t = 0; t < 4; ++t) {
      async_ld16(gh + (size_t)t * 512 + lane * 8, lh + t * 512);
      async_ld16(gl + (size_t)t * 512 + lane * 8, llo + t * 512);
    }
    asm volatile("s_waitcnt vmcnt(0)" ::: "memory");
#pragma unroll
    for (int t = 0; t < 4; ++t) {
      bf16x8 bh = *(const bf16x8*)&lh[t * 512 + lane * 8];
      bf16x8 bl = *(const bf16x8*)&llo[t * 512 + lane * 8];
      int f = ct * 4 + t;
      acc[f] = __builtin_amdgcn_mfma_f32_16x16x32_bf16(ahi, bh, acc[f], 0, 0, 0);
      acc[f] = __builtin_amdgcn_mfma_f32_16x16x32_bf16(ahi, bl, acc[f], 0, 0, 0);
      acc[f] = __builtin_amdgcn_mfma_f32_16x16x32_bf16(alo, bh, acc[f], 0, 0, 0);
    }
    asm volatile("" ::: "memory");  // keep staging of next chunk after these reads
  }

  // ---- row max over this wave's 256 cols
  float mrow[4];
#pragma unroll
  for (int r = 0; r < 4; ++r) {
    float m = acc[0][r];
#pragma unroll
    for (int f = 1; f < 16; ++f) m = fmaxf(m, acc[f][r]);
    mrow[r] = m;
  }
#pragma unroll
  for (int mask = 1; mask < 16; mask <<= 1)
#pragma unroll
    for (int r = 0; r < 4; ++r) mrow[r] = fmaxf(mrow[r], __shfl_xor(mrow[r], mask));
  if (ln == 0) {
#pragma unroll
    for (int r = 0; r < 4; ++r) red[wave][quad * 4 + r] = mrow[r];
  }
  __syncthreads();   // after this barrier all kbuf reads are done -> shm reusable
  float gmax[4];
#pragma unroll
  for (int r = 0; r < 4; ++r)
    gmax[r] = fmaxf(fmaxf(red[0][quad * 4 + r], red[1][quad * 4 + r]),
                    fmaxf(red[2][quad * 4 + r], red[3][quad * 4 + r]));
  __syncthreads();

  // ---- exp + row sum
  float ssum[4] = {0.f, 0.f, 0.f, 0.f};
#pragma unroll
  for (int f = 0; f < 16; ++f)
#pragma unroll
    for (int r = 0; r < 4; ++r) {
      float e = __expf(acc[f][r] - gmax[r]);
      acc[f][r] = e;
      ssum[r] += e;
    }
#pragma unroll
  for (int mask = 1; mask < 16; mask <<= 1)
#pragma unroll
    for (int r = 0; r < 4; ++r) ssum[r] += __shfl_xor(ssum[r], mask);
  if (ln == 0) {
#pragma unroll
    for (int r = 0; r < 4; ++r) red[wave][quad * 4 + r] = ssum[r];
  }
  __syncthreads();
  float inv[4];
#pragma unroll
  for (int r = 0; r < 4; ++r)
    inv[r] = 1.0f / (red[0][quad * 4 + r] + red[1][quad * 4 + r] +
                     red[2][quad * 4 + r] + red[3][quad * 4 + r]);

  // ---- normalize: store att f32 (required output) + transpose P bf16 into LDS
  // P_lds[m][j] at ushort index m*1024 + (j ^ ((m&7)<<3))  (16B-granular XOR
  // swizzle: PV-phase ds_read_b128 across rows m=0..15 covers all 32 banks)
  float* attB = att + (size_t)b * LL * LL;
#pragma unroll
  for (int r = 0; r < 4; ++r) {
    int m = quad * 4 + r;
    size_t rowoff = (size_t)(i0 + m) * LL;
#pragma unroll
    for (int f = 0; f < 16; ++f) {
      int col = wave * 256 + f * 16 + ln;
      float p = acc[f][r] * inv[r];
      attB[rowoff + col] = p;
      shm[m * 1024 + (col ^ ((m & 7) << 3))] = f2bu(p);
    }
  }
  __syncthreads();

  // ---- PV: out[c, i0+m] = gamma * sum_j V[c,j] P[m,j] + x[c, i0+m]
  // wave owns c in [wave*64, wave*64+64); A = V fragments direct from global
  // (L2-resident: 512KB per batch), B = P from swizzled LDS.
  const ushort* vbB = vbf + (size_t)b * CC * LL;
  int cb = wave * 64;
  f32x4 accO[4];
#pragma unroll
  for (int i = 0; i < 4; ++i) accO[i] = {0.f, 0.f, 0.f, 0.f};

  for (int jc = 0; jc < 32; ++jc) {
    bf16x8 pb = *(const bf16x8*)&shm[ln * 1024 + ((jc * 32 + quad * 8) ^ ((ln & 7) << 3))];
    bf16x8 af[4];
#pragma unroll
    for (int i = 0; i < 4; ++i)
      af[i] = *(const bf16x8*)&vbB[(size_t)(cb + i * 16 + ln) * LL + jc * 32 + quad * 8];
#pragma unroll
    for (int i = 0; i < 4; ++i)
      accO[i] = __builtin_amdgcn_mfma_f32_16x16x32_bf16(af[i], pb, accO[i], 0, 0, 0);
  }

  float g = gamma[0];
  const float* xb = x + (size_t)b * CC * LL;
  float* ob = out + (size_t)b * CC * LL;
#pragma unroll
  for (int i = 0; i < 4; ++i) {
#pragma unroll
    for (int r = 0; r < 4; ++r) {
      int c = cb + i * 16 + quad * 4 + r;
      size_t idx = (size_t)c * LL + i0 + ln;
      ob[idx] = fmaf(g, accO[i][r], xb[idx]);
    }
  }
}

extern "C" void kernel_launch(void* const* d_in, const int* in_sizes, int n_in,
                              void* d_out, int out_size, void* d_ws, size_t ws_size,
                              hipStream_t stream) {
  const float* x = (const float*)d_in[0];
  const float* Wq = (const float*)d_in[1];
  const float* bq = (const float*)d_in[2];
  const float* Wk = (const float*)d_in[3];
  const float* bk = (const float*)d_in[4];
  const float* Wv = (const float*)d_in[5];
  const float* bv = (const float*)d_in[6];
  const float* gamma = (const float*)d_in[7];

  float* out = (float*)d_out;
  float* att = out + (size_t)BB * CC * LL;

  float* wsf = (float*)d_ws;
  float* Wcat = wsf + WCAT_OFF;
  float* bcat = wsf + BCAT_OFF;
  float* qk = wsf + QK_OFF;
  ushort* usbase = (ushort*)(wsf + US_BASE);
  ushort* vbf = usbase + VBF_OFF;
  ushort* Wvbf = usbase + WVBF_OFF;
  ushort* xT = usbase + XT_OFF;
  ushort* kth = usbase + KTH_OFF;
  ushort* ktl = usbase + KTL_OFF;

  pack_w_kernel<<<dim3(OTOT), dim3(CC), 0, stream>>>(Wq, bq, Wk, bk, Wv, bv, Wcat, bcat, Wvbf);
  xT_kernel<<<dim3(LL / 64, CC / 64, BB), dim3(256), 0, stream>>>(x, xT);
  proj_qk_kernel<<<dim3(LL / 64, 1, BB), dim3(256), 0, stream>>>(x, Wcat, bcat, qk);
  kT_pack_kernel<<<dim3(4, BB), dim3(256), 0, stream>>>(qk, kth, ktl);
  v_mfma_kernel<<<dim3(LL / 128, CC / 128, BB), dim3(256), 0, stream>>>(Wvbf, xT, bv, vbf);
  attn_fused_kernel<<<dim3(LL / 16, BB), dim3(256), 0, stream>>>(qk, kth, ktl, vbf, x, gamma, att, out);
}

// Round 4
// 317.510 us; speedup vs baseline: 1.1310x; 1.1310x over previous
//
#include <hip/hip_runtime.h>
#include <hip/hip_bf16.h>

#define BB 32
#define CC 256
#define CQK 32
#define LL 1024
#define OTOT 320

// ---------------- workspace layout ----------------
// float region:
#define WCAT_OFF 0
#define BCAT_OFF (OTOT * CC)                 // 81920
#define QK_OFF   (BCAT_OFF + OTOT)           // 82240
#define QK_SIZE  (BB * 64 * LL)              // 2097152
#define US_BASE  (QK_OFF + QK_SIZE)          // 2179392 floats (byte 8717568, 16B aligned)
// ushort region (offsets in ushorts from US_BASE):
#define VBF_OFF   ((size_t)0)
#define ATTBF_OFF ((size_t)BB * CC * LL)                  // 8388608
#define WVBF_OFF  (ATTBF_OFF + (size_t)BB * LL * LL)      // 41943040
#define XT_OFF    (WVBF_OFF + (size_t)CC * CC)            // 42008576
#define KTH_OFF   (XT_OFF + (size_t)BB * LL * CC)         // 50397184
#define KTL_OFF   (KTH_OFF + (size_t)BB * LL * 32)        // 51445760

typedef __bf16 bf16x8 __attribute__((ext_vector_type(8)));
typedef float f32x4 __attribute__((ext_vector_type(4)));

__device__ inline void async_ld16(const void* g, void* l) {
  __builtin_amdgcn_global_load_lds(
      (const __attribute__((address_space(1))) void*)g,
      (__attribute__((address_space(3))) void*)l, 16, 0, 0);
}

__device__ inline ushort f2bu(float f) {
  union { __hip_bfloat16 h; ushort u; } c;
  c.h = __float2bfloat16(f);
  return c.u;
}
__device__ inline float bu2f(ushort u) {
  union { __hip_bfloat16 h; ushort u; } c;
  c.u = u;
  return __bfloat162float(c.h);
}

// ---------------------------------------------------------------- pack W+b
__global__ __launch_bounds__(256) void pack_w_kernel(
    const float* __restrict__ Wq, const float* __restrict__ bq,
    const float* __restrict__ Wk, const float* __restrict__ bk,
    const float* __restrict__ Wv, const float* __restrict__ bv,
    float* __restrict__ Wcat, float* __restrict__ bcat,
    ushort* __restrict__ Wvbf) {
  int o = blockIdx.x;
  int c = threadIdx.x;
  float w = (o < CQK) ? Wq[o * CC + c]
          : (o < 2 * CQK) ? Wk[(o - CQK) * CC + c]
          : Wv[(o - 2 * CQK) * CC + c];
  Wcat[o * CC + c] = w;
  if (o >= 64) Wvbf[(o - 64) * CC + c] = f2bu(w);
  if (c == 0) {
    bcat[o] = (o < CQK) ? bq[o] : (o < 2 * CQK) ? bk[o - CQK] : bv[o - 2 * CQK];
  }
}

// -------------------------------------------- x transpose: [b][c][l] -> bf16 [b][l][c]
__global__ __launch_bounds__(256) void xT_kernel(
    const float* __restrict__ x, ushort* __restrict__ xT) {
  __shared__ float t[64][65];
  int b = blockIdx.z, c0 = blockIdx.y * 64, l0 = blockIdx.x * 64;
  int tid = threadIdx.x;
  int r = tid >> 4, c4 = (tid & 15) * 4;
  const float* xb = x + ((size_t)b * CC + c0) * LL + l0;
#pragma unroll
  for (int i = 0; i < 4; ++i) {
    float4 v = *(const float4*)&xb[(size_t)(r + i * 16) * LL + c4];
    t[r + i * 16][c4 + 0] = v.x;
    t[r + i * 16][c4 + 1] = v.y;
    t[r + i * 16][c4 + 2] = v.z;
    t[r + i * 16][c4 + 3] = v.w;
  }
  __syncthreads();
  ushort* xo = xT + ((size_t)b * LL + l0) * CC + c0;
#pragma unroll
  for (int i = 0; i < 4; ++i) {
    int l = r + i * 16;
    ushort4 u;
    u.x = f2bu(t[c4 + 0][l]);
    u.y = f2bu(t[c4 + 1][l]);
    u.z = f2bu(t[c4 + 2][l]);
    u.w = f2bu(t[c4 + 3][l]);
    *(ushort4*)&xo[(size_t)l * CC + c4] = u;
  }
}

// ------------------------------------------------- q/k projection (fp32 VALU)
#define PPITCH 68
__global__ __launch_bounds__(256) void proj_qk_kernel(
    const float* __restrict__ x, const float* __restrict__ Wcat,
    const float* __restrict__ bcat, float* __restrict__ qk) {
  __shared__ float ws[32][PPITCH];
  __shared__ float xs[32][PPITCH];
  int b = blockIdx.z;
  int l0 = blockIdx.x * 64;
  int tid = threadIdx.x;
  int tx = tid & 15, ty = tid >> 4;
  const float* xb = x + (size_t)b * CC * LL;
  float acc[4][4] = {};

  for (int c0 = 0; c0 < CC; c0 += 32) {
    __syncthreads();
    {
      int o = tid >> 5;
      int kk = tid & 31;
#pragma unroll
      for (int r = 0; r < 8; ++r)
        ws[kk][o + 8 * r] = Wcat[(o + 8 * r) * CC + c0 + kk];
      int l = tid & 63;
      int k4 = tid >> 6;
#pragma unroll
      for (int r = 0; r < 8; ++r)
        xs[k4 + 4 * r][l] = xb[(size_t)(c0 + k4 + 4 * r) * LL + l0 + l];
    }
    __syncthreads();
#pragma unroll 8
    for (int kk = 0; kk < 32; ++kk) {
      float a[4], bvv[4];
      *(float4*)a = *(const float4*)&ws[kk][ty * 4];
      *(float4*)bvv = *(const float4*)&xs[kk][tx * 4];
#pragma unroll
      for (int i = 0; i < 4; ++i)
#pragma unroll
        for (int j = 0; j < 4; ++j)
          acc[i][j] = fmaf(a[i], bvv[j], acc[i][j]);
    }
  }
#pragma unroll
  for (int i = 0; i < 4; ++i) {
    int o = ty * 4 + i;
    float bias = bcat[o];
    float4 r;
    r.x = acc[i][0] + bias;
    r.y = acc[i][1] + bias;
    r.z = acc[i][2] + bias;
    r.w = acc[i][3] + bias;
    *(float4*)&qk[((size_t)b * 64 + o) * LL + l0 + tx * 4] = r;
  }
}

// ---------------- pack k rows into B-fragment order, hi/lo bf16
// kTp[b][jt][(q*16+l16)*8+jj] = k[b][k=q*8+jj][j=jt*16+l16]
// 512 blocks (was 128: 0.5 blocks/CU left half the GPU idle).
// Each block: 64-col group. XCD-chunk swizzle for qk L2 locality.
__global__ __launch_bounds__(256) void kT_pack_kernel(
    const float* __restrict__ qk, ushort* __restrict__ kth,
    ushort* __restrict__ ktl) {
  __shared__ float ks[32][68];  // 32 k-rows x 64 cols (+pad, 16B-aligned rows)
  int id = blockIdx.x;
  int nid = (id & 7) * 64 + (id >> 3);   // bijective: 512 = 8 * 64
  int b = nid >> 4, jg = nid & 15;       // jg: 64-col group
  int tid = threadIdx.x;
  const float* kb = qk + ((size_t)b * 64 + CQK) * LL + jg * 64;
  {
    int row = tid >> 4;            // 0..15
    int col4 = (tid & 15) * 4;
    float4 v0 = *(const float4*)&kb[(size_t)row * LL + col4];
    float4 v1 = *(const float4*)&kb[(size_t)(row + 16) * LL + col4];
    *(float4*)&ks[row][col4] = v0;
    *(float4*)&ks[row + 16][col4] = v1;
  }
  __syncthreads();
  int jt_l = tid >> 6;           // 0..3  (jt = jg*4 + jt_l)
  int q = (tid >> 4) & 3;        // k-quad
  int l16 = tid & 15;            // col within jt
  ushort h[8], lo[8];
#pragma unroll
  for (int jj = 0; jj < 8; ++jj) {
    float v = ks[q * 8 + jj][jt_l * 16 + l16];
    ushort hh = f2bu(v);
    h[jj] = hh;
    lo[jj] = f2bu(v - bu2f(hh));
  }
  size_t off = (((size_t)b * 64 + jg * 4 + jt_l) * 64 + (q * 16 + l16)) * 8;
  *(ushort4*)&kth[off] = *(ushort4*)&h[0];
  *(ushort4*)&kth[off + 4] = *(ushort4*)&h[4];
  *(ushort4*)&ktl[off] = *(ushort4*)&lo[0];
  *(ushort4*)&ktl[off + 4] = *(ushort4*)&lo[4];
}

// ---------------- v projection: vbf[b][c][l] = bf16( Wv·x + bv ), MFMA
// (round-0 verified single-buffer structure; 3-D grid already XCD-friendly)
__global__ __launch_bounds__(256) void v_mfma_kernel(
    const ushort* __restrict__ Wvbf, const ushort* __restrict__ xT,
    const float* __restrict__ bv, ushort* __restrict__ vbf) {
  __shared__ ushort As[128 * 32];
  __shared__ ushort Bs[128 * 32];
  int b = blockIdx.z;
  int c0 = blockIdx.y * 128;
  int l0 = blockIdx.x * 128;
  int tid = threadIdx.x;
  int wave = tid >> 6, lane = tid & 63;
  int quad = lane >> 4, ln = lane & 15;
  int wr = (wave >> 1) * 64;
  int wc = (wave & 1) * 64;
  const ushort* xb = xT + (size_t)b * LL * CC;
  int r0 = tid >> 2, r1 = r0 + 64;
  int cq = (tid & 3) * 8;
  ushort* lA0 = As + (size_t)(wave * 64) * 8;
  ushort* lA1 = As + (size_t)(256 + wave * 64) * 8;
  ushort* lB0 = Bs + (size_t)(wave * 64) * 8;
  ushort* lB1 = Bs + (size_t)(256 + wave * 64) * 8;

  f32x4 acc[4][4];
#pragma unroll
  for (int i = 0; i < 4; ++i)
#pragma unroll
    for (int j = 0; j < 4; ++j) acc[i][j] = {0.f, 0.f, 0.f, 0.f};

  for (int kt = 0; kt < CC; kt += 32) {
    __syncthreads();
    async_ld16(Wvbf + (size_t)(c0 + r0) * CC + kt + cq, lA0);
    async_ld16(Wvbf + (size_t)(c0 + r1) * CC + kt + cq, lA1);
    async_ld16(xb + (size_t)(l0 + r0) * CC + kt + cq, lB0);
    async_ld16(xb + (size_t)(l0 + r1) * CC + kt + cq, lB1);
    __syncthreads();
    bf16x8 af[4], bfr[4];
#pragma unroll
    for (int i = 0; i < 4; ++i)
      af[i] = *(const bf16x8*)&As[(size_t)(wr + i * 16 + ln) * 32 + quad * 8];
#pragma unroll
    for (int j = 0; j < 4; ++j)
      bfr[j] = *(const bf16x8*)&Bs[(size_t)(wc + j * 16 + ln) * 32 + quad * 8];
#pragma unroll
    for (int i = 0; i < 4; ++i)
#pragma unroll
      for (int j = 0; j < 4; ++j)
        acc[i][j] = __builtin_amdgcn_mfma_f32_16x16x32_bf16(af[i], bfr[j], acc[i][j], 0, 0, 0);
  }

  ushort* vb = vbf + (size_t)b * CC * LL;
#pragma unroll
  for (int i = 0; i < 4; ++i) {
#pragma unroll
    for (int r = 0; r < 4; ++r) {
      int c = c0 + wr + i * 16 + quad * 4 + r;
      float bias = bv[c];
#pragma unroll
      for (int j = 0; j < 4; ++j) {
        int l = l0 + wc + j * 16 + ln;
        vb[(size_t)c * LL + l] = f2bu(acc[i][j][r] + bias);
      }
    }
  }
}

// ---------------- fused scores (hi/lo MFMA) + softmax -> att fp32 + attbf bf16
// block: 16 att rows x 1024 cols; wave w owns cols [w*256, w*256+256)
// 1-D grid 2048 with bijective XCD-chunk swizzle: 256 blocks (=4 whole
// batches) per XCD -> kth/ktl stay in one XCD's L2.
__global__ __launch_bounds__(256) void scores_softmax_kernel(
    const float* __restrict__ qk, const ushort* __restrict__ kth,
    const ushort* __restrict__ ktl, float* __restrict__ att,
    ushort* __restrict__ attbf) {
  __shared__ float qs[32][17];
  __shared__ ushort kbuf[4][2][2048];  // [wave][hi/lo][64 cols x 32 k]  (32 KB)
  __shared__ float red[4][16];
  int id = blockIdx.x;
  int nid = (id & 7) * 256 + (id >> 3);  // bijective: 2048 = 8 * 256
  int b = nid >> 6;
  int i0 = (nid & 63) * 16;
  int tid = threadIdx.x;
  int wave = tid >> 6, lane = tid & 63;
  int quad = lane >> 4, ln = lane & 15;

  // stage q tile [32 d][16 rows]
  const float* qb = qk + (size_t)b * 64 * LL;
  {
    int e0 = tid, e1 = tid + 256;
    qs[e0 >> 4][e0 & 15] = qb[(size_t)(e0 >> 4) * LL + i0 + (e0 & 15)];
    qs[e1 >> 4][e1 & 15] = qb[(size_t)(e1 >> 4) * LL + i0 + (e1 & 15)];
  }
  __syncthreads();

  // A fragments hi/lo: A[m=ln][k=quad*8+jj]
  bf16x8 ahi, alo;
  {
    union { bf16x8 v; ushort u[8]; } H, L;
#pragma unroll
    for (int jj = 0; jj < 8; ++jj) {
      float v = qs[quad * 8 + jj][ln];
      ushort hh = f2bu(v);
      H.u[jj] = hh;
      L.u[jj] = f2bu(v - bu2f(hh));
    }
    ahi = H.v;
    alo = L.v;
  }

  const ushort* khB = kth + (size_t)b * LL * 32;
  const ushort* klB = ktl + (size_t)b * LL * 32;
  ushort* lh = &kbuf[wave][0][0];
  ushort* llo = &kbuf[wave][1][0];

  f32x4 acc[16];
#pragma unroll
  for (int f = 0; f < 16; ++f) acc[f] = {0.f, 0.f, 0.f, 0.f};

  for (int ct = 0; ct < 4; ++ct) {
    int jt0 = wave * 16 + ct * 4;
    const ushort* gh = khB + (size_t)jt0 * 512;
    const ushort* gl = klB + (size_t)jt0 * 512;
#pragma unroll
    for (int t = 0; t < 4; ++t) {
      async_ld16(gh + (size_t)t * 512 + lane * 8, lh + t * 512);
      async_ld16(gl + (size_t)t * 512 + lane * 8, llo + t * 512);
    }
    asm volatile("s_waitcnt vmcnt(0)" ::: "memory");
#pragma unroll
    for (int t = 0; t < 4; ++t) {
      bf16x8 bh = *(const bf16x8*)&lh[t * 512 + lane * 8];
      bf16x8 bl = *(const bf16x8*)&llo[t * 512 + lane * 8];
      int f = ct * 4 + t;
      acc[f] = __builtin_amdgcn_mfma_f32_16x16x32_bf16(ahi, bh, acc[f], 0, 0, 0);
      acc[f] = __builtin_amdgcn_mfma_f32_16x16x32_bf16(ahi, bl, acc[f], 0, 0, 0);
      acc[f] = __builtin_amdgcn_mfma_f32_16x16x32_bf16(alo, bh, acc[f], 0, 0, 0);
    }
    asm volatile("" ::: "memory");  // keep staging of next chunk after these reads
  }

  // ---- row max over this wave's 256 cols
  float mrow[4];
#pragma unroll
  for (int r = 0; r < 4; ++r) {
    float m = acc[0][r];
#pragma unroll
    for (int f = 1; f < 16; ++f) m = fmaxf(m, acc[f][r]);
    mrow[r] = m;
  }
#pragma unroll
  for (int mask = 1; mask < 16; mask <<= 1)
#pragma unroll
    for (int r = 0; r < 4; ++r) mrow[r] = fmaxf(mrow[r], __shfl_xor(mrow[r], mask));
  if (ln == 0) {
#pragma unroll
    for (int r = 0; r < 4; ++r) red[wave][quad * 4 + r] = mrow[r];
  }
  __syncthreads();
  float gmax[4];
#pragma unroll
  for (int r = 0; r < 4; ++r)
    gmax[r] = fmaxf(fmaxf(red[0][quad * 4 + r], red[1][quad * 4 + r]),
                    fmaxf(red[2][quad * 4 + r], red[3][quad * 4 + r]));
  __syncthreads();

  // ---- exp + row sum
  float ssum[4] = {0.f, 0.f, 0.f, 0.f};
#pragma unroll
  for (int f = 0; f < 16; ++f)
#pragma unroll
    for (int r = 0; r < 4; ++r) {
      float e = __expf(acc[f][r] - gmax[r]);
      acc[f][r] = e;
      ssum[r] += e;
    }
#pragma unroll
  for (int mask = 1; mask < 16; mask <<= 1)
#pragma unroll
    for (int r = 0; r < 4; ++r) ssum[r] += __shfl_xor(ssum[r], mask);
  if (ln == 0) {
#pragma unroll
    for (int r = 0; r < 4; ++r) red[wave][quad * 4 + r] = ssum[r];
  }
  __syncthreads();
  float inv[4];
#pragma unroll
  for (int r = 0; r < 4; ++r)
    inv[r] = 1.0f / (red[0][quad * 4 + r] + red[1][quad * 4 + r] +
                     red[2][quad * 4 + r] + red[3][quad * 4 + r]);

  // ---- normalize + store
  float* attB = att + (size_t)b * LL * LL;
  ushort* attbfB = attbf + (size_t)b * LL * LL;
#pragma unroll
  for (int r = 0; r < 4; ++r) {
    size_t rowoff = (size_t)(i0 + quad * 4 + r) * LL;
#pragma unroll
    for (int f = 0; f < 16; ++f) {
      int col = wave * 256 + f * 16 + ln;
      float p = acc[f][r] * inv[r];
      attB[rowoff + col] = p;
      attbfB[rowoff + col] = f2bu(p);
    }
  }
}

// ------------- out[b][c][m] = gamma * sum_l v[c][l]*att[m][l] + x  (bf16 MFMA)
// 1-D grid 512 with bijective XCD-chunk swizzle: 64 blocks (=4 whole batches)
// per XCD -> vbf (512 KB/batch) fetched once per XCD instead of 8x.
__global__ __launch_bounds__(256) void out_mfma_kernel(
    const ushort* __restrict__ vbf, const ushort* __restrict__ attbf,
    const float* __restrict__ x, const float* __restrict__ gamma,
    float* __restrict__ out) {
  __shared__ ushort As[128 * 32];
  __shared__ ushort Bs[128 * 32];
  int id = blockIdx.x;
  int nid = (id & 7) * 64 + (id >> 3);   // bijective: 512 = 8 * 64
  int b = nid >> 4;
  int rem = nid & 15;
  int c0 = (rem >> 3) * 128;
  int m0 = (rem & 7) * 128;
  int tid = threadIdx.x;
  int wave = tid >> 6, lane = tid & 63;
  int quad = lane >> 4, ln = lane & 15;
  int wr = (wave >> 1) * 64;
  int wc = (wave & 1) * 64;

  const ushort* vb = vbf + (size_t)b * CC * LL;
  const ushort* ab = attbf + (size_t)b * LL * LL;

  int r0 = tid >> 2, r1 = r0 + 64;
  int cq = (tid & 3) * 8;
  ushort* lA0 = As + (size_t)(wave * 64) * 8;
  ushort* lA1 = As + (size_t)(256 + wave * 64) * 8;
  ushort* lB0 = Bs + (size_t)(wave * 64) * 8;
  ushort* lB1 = Bs + (size_t)(256 + wave * 64) * 8;

  f32x4 acc[4][4];
#pragma unroll
  for (int i = 0; i < 4; ++i)
#pragma unroll
    for (int j = 0; j < 4; ++j) acc[i][j] = {0.f, 0.f, 0.f, 0.f};

  for (int kt = 0; kt < LL; kt += 32) {
    __syncthreads();
    async_ld16(vb + (size_t)(c0 + r0) * LL + kt + cq, lA0);
    async_ld16(vb + (size_t)(c0 + r1) * LL + kt + cq, lA1);
    async_ld16(ab + (size_t)(m0 + r0) * LL + kt + cq, lB0);
    async_ld16(ab + (size_t)(m0 + r1) * LL + kt + cq, lB1);
    __syncthreads();

    bf16x8 af[4], bfr[4];
#pragma unroll
    for (int i = 0; i < 4; ++i)
      af[i] = *(const bf16x8*)&As[(size_t)(wr + i * 16 + ln) * 32 + quad * 8];
#pragma unroll
    for (int j = 0; j < 4; ++j)
      bfr[j] = *(const bf16x8*)&Bs[(size_t)(wc + j * 16 + ln) * 32 + quad * 8];
#pragma unroll
    for (int i = 0; i < 4; ++i)
#pragma unroll
      for (int j = 0; j < 4; ++j)
        acc[i][j] = __builtin_amdgcn_mfma_f32_16x16x32_bf16(af[i], bfr[j], acc[i][j], 0, 0, 0);
  }

  float g = gamma[0];
  const float* xb = x + (size_t)b * CC * LL;
  float* ob = out + (size_t)b * CC * LL;
#pragma unroll
  for (int i = 0; i < 4; ++i) {
#pragma unroll
    for (int r = 0; r < 4; ++r) {
      int c = c0 + wr + i * 16 + quad * 4 + r;
#pragma unroll
      for (int j = 0; j < 4; ++j) {
        int m = m0 + wc + j * 16 + ln;
        size_t idx = (size_t)c * LL + m;
        ob[idx] = fmaf(g, acc[i][j][r], xb[idx]);
      }
    }
  }
}

extern "C" void kernel_launch(void* const* d_in, const int* in_sizes, int n_in,
                              void* d_out, int out_size, void* d_ws, size_t ws_size,
                              hipStream_t stream) {
  const float* x = (const float*)d_in[0];
  const float* Wq = (const float*)d_in[1];
  const float* bq = (const float*)d_in[2];
  const float* Wk = (const float*)d_in[3];
  const float* bk = (const float*)d_in[4];
  const float* Wv = (const float*)d_in[5];
  const float* bv = (const float*)d_in[6];
  const float* gamma = (const float*)d_in[7];

  float* out = (float*)d_out;
  float* att = out + (size_t)BB * CC * LL;

  float* wsf = (float*)d_ws;
  float* Wcat = wsf + WCAT_OFF;
  float* bcat = wsf + BCAT_OFF;
  float* qk = wsf + QK_OFF;
  ushort* usbase = (ushort*)(wsf + US_BASE);
  ushort* vbf = usbase + VBF_OFF;
  ushort* attbf = usbase + ATTBF_OFF;
  ushort* Wvbf = usbase + WVBF_OFF;
  ushort* xT = usbase + XT_OFF;
  ushort* kth = usbase + KTH_OFF;
  ushort* ktl = usbase + KTL_OFF;

  pack_w_kernel<<<dim3(OTOT), dim3(CC), 0, stream>>>(Wq, bq, Wk, bk, Wv, bv, Wcat, bcat, Wvbf);
  xT_kernel<<<dim3(LL / 64, CC / 64, BB), dim3(256), 0, stream>>>(x, xT);
  proj_qk_kernel<<<dim3(LL / 64, 1, BB), dim3(256), 0, stream>>>(x, Wcat, bcat, qk);
  kT_pack_kernel<<<dim3(512), dim3(256), 0, stream>>>(qk, kth, ktl);
  v_mfma_kernel<<<dim3(LL / 128, CC / 128, BB), dim3(256), 0, stream>>>(Wvbf, xT, bv, vbf);
  scores_softmax_kernel<<<dim3(2048), dim3(256), 0, stream>>>(qk, kth, ktl, att, attbf);
  out_mfma_kernel<<<dim3(512), dim3(256), 0, stream>>>(vbf, attbf, x, gamma, out);
}